// Round 1
// baseline (70.892 us; speedup 1.0000x reference)
//
#include <hip/hip_runtime.h>

// MesoLayer: for each of 7 segments (L in {5,9,9,25,9,9,12}) of x[B,78,5]:
//   fw = sub @ W (5->10); s = fw.sum(j); scores[j] = fw[j]·s
//   == sub[j]ᵀ (W Wᵀ) subsum  -> softmax over j -> pooled = Σ att[j] sub[j]
// Output: [B,7,5] float32.

template<int L>
__device__ __forceinline__ void process_seg(const float* __restrict__ xr,
                                            const float (&M)[5][5],
                                            float* __restrict__ op) {
    float sub[L][5];
#pragma unroll
    for (int j = 0; j < L; ++j)
#pragma unroll
        for (int g = 0; g < 5; ++g)
            sub[j][g] = xr[j * 5 + g];

    // subsum over j
    float ss[5] = {0.f, 0.f, 0.f, 0.f, 0.f};
#pragma unroll
    for (int j = 0; j < L; ++j)
#pragma unroll
        for (int g = 0; g < 5; ++g)
            ss[g] += sub[j][g];

    // v = M · subsum   (M symmetric, orientation irrelevant)
    float v[5];
#pragma unroll
    for (int g = 0; g < 5; ++g) {
        float a = 0.f;
#pragma unroll
        for (int h = 0; h < 5; ++h) a += M[g][h] * ss[h];
        v[g] = a;
    }

    // scores + running max
    float sc[L];
    float m = -1e30f;
#pragma unroll
    for (int j = 0; j < L; ++j) {
        float a = 0.f;
#pragma unroll
        for (int g = 0; g < 5; ++g) a += sub[j][g] * v[g];
        sc[j] = a;
        m = fmaxf(m, a);
    }

    // softmax-weighted pool in one pass
    float denom = 0.f;
    float pooled[5] = {0.f, 0.f, 0.f, 0.f, 0.f};
#pragma unroll
    for (int j = 0; j < L; ++j) {
        float e = __expf(sc[j] - m);
        denom += e;
#pragma unroll
        for (int g = 0; g < 5; ++g) pooled[g] += e * sub[j][g];
    }
    float inv = 1.0f / denom;
#pragma unroll
    for (int g = 0; g < 5; ++g) op[g] = pooled[g] * inv;
}

__global__ __launch_bounds__(256) void meso_kernel(const float* __restrict__ x,
                                                   const float* __restrict__ w,
                                                   float* __restrict__ out,
                                                   int B) {
    int b = blockIdx.x * 256 + threadIdx.x;
    if (b >= B) return;

    // M = W Wᵀ (5x5). w is uniform across threads -> scalar loads.
    float W[5][10];
#pragma unroll
    for (int g = 0; g < 5; ++g)
#pragma unroll
        for (int h = 0; h < 10; ++h)
            W[g][h] = w[g * 10 + h];

    float M[5][5];
#pragma unroll
    for (int g = 0; g < 5; ++g)
#pragma unroll
        for (int gp = 0; gp < 5; ++gp) {
            float a = 0.f;
#pragma unroll
            for (int h = 0; h < 10; ++h) a += W[g][h] * W[gp][h];
            M[g][gp] = a;
        }

    const float* xr = x + (size_t)b * 390;   // 78*5
    float*       op = out + (size_t)b * 35;  // 7*5

    // Segment element offsets: cumsum(L)*5
    process_seg<5 >(xr + 0,   M, op + 0);
    process_seg<9 >(xr + 25,  M, op + 5);
    process_seg<9 >(xr + 70,  M, op + 10);
    process_seg<25>(xr + 115, M, op + 15);
    process_seg<9 >(xr + 240, M, op + 20);
    process_seg<9 >(xr + 285, M, op + 25);
    process_seg<12>(xr + 330, M, op + 30);
}

extern "C" void kernel_launch(void* const* d_in, const int* in_sizes, int n_in,
                              void* d_out, int out_size, void* d_ws, size_t ws_size,
                              hipStream_t stream) {
    const float* x = (const float*)d_in[0];
    const float* w = (const float*)d_in[1];
    float* out = (float*)d_out;
    int B = in_sizes[0] / 390;               // 131072
    int grid = (B + 255) / 256;
    meso_kernel<<<grid, 256, 0, stream>>>(x, w, out, B);
}

// Round 2
// 64.232 us; speedup vs baseline: 1.1037x; 1.1037x over previous
//
#include <hip/hip_runtime.h>

// MesoLayer, coalesced LDS-staged version.
// For each of 7 segments (L in {5,9,9,25,9,9,12}) of x[B,78,5]:
//   scores[j] = sub[j]^T (W W^T) subsum -> softmax_j -> pooled = sum att[j] sub[j]
// Block: 128 threads = 128 rows. 2-phase pipeline: stage(seg k+1) via
// global_load_lds (async, coalesced) overlapped with compute(seg k) from LDS.
// Seg L=25 split into 16j + 9j staging units so all concurrent buffer pairs
// fit in 64512 B static LDS (2 blocks/CU).

#define GLL4(gp, lp)                                                    \
  __builtin_amdgcn_global_load_lds(                                     \
      (const __attribute__((address_space(1))) void*)(gp),              \
      (__attribute__((address_space(3))) void*)(lp), 4, 0, 0)

// Stage one unit: 128 rows x P floats (S useful, P-S pad clamped to elem 0).
// LDS element e = i*128 + t  <->  (row = e/P, o = e%P), so the LDS dest is
// lane-linear (global_load_lds requirement) and the global side is coalesced
// in runs of S contiguous floats per row.
template<int P, int S, int SRC, int LDSOFF>
__device__ __forceinline__ void stage_unit(const float* __restrict__ x,
                                           int row0, int t, float* sm) {
  constexpr int Q = 128 / P;
  constexpr int R = 128 % P;
  int row = t / P;            // constexpr P -> magic div
  int o   = t - row * P;
#pragma unroll 4
  for (int i = 0; i < P; ++i) {
    int osrc = (o < S) ? o : 0;                       // clamp pad cells
    const float* g = x + (size_t)(row0 + row) * 390 + (SRC + osrc);
    GLL4(g, sm + LDSOFF + i * 128 + t);
    o += R; row += Q;
    if (o >= P) { o -= P; ++row; }
  }
}

// Full segment compute for row t from LDS region (stride P, P odd -> no bank
// conflicts: (t*P + c) mod 32 distinct per lane).
template<int L, int P, int LDSOFF, int OUTOFF>
__device__ __forceinline__ void compute_seg(const float* sm, int t,
                                            const float (&M)[5][5],
                                            float (&outv)[35]) {
  const float* bp = sm + LDSOFF + t * P;
  float ss[5] = {0.f, 0.f, 0.f, 0.f, 0.f};
#pragma unroll
  for (int j = 0; j < L; ++j)
#pragma unroll
    for (int g = 0; g < 5; ++g) ss[g] += bp[j * 5 + g];

  float v[5];
#pragma unroll
  for (int g = 0; g < 5; ++g) {
    float a = 0.f;
#pragma unroll
    for (int h = 0; h < 5; ++h) a += M[g][h] * ss[h];
    v[g] = a;
  }

  float sc[L];
  float m = -1e30f;
#pragma unroll
  for (int j = 0; j < L; ++j) {
    float a = 0.f;
#pragma unroll
    for (int g = 0; g < 5; ++g) a += bp[j * 5 + g] * v[g];
    sc[j] = a;
    m = fmaxf(m, a);
  }

  float d = 0.f, p5[5] = {0.f, 0.f, 0.f, 0.f, 0.f};
#pragma unroll
  for (int j = 0; j < L; ++j) {
    float e = __expf(sc[j] - m);
    d += e;
#pragma unroll
    for (int g = 0; g < 5; ++g) p5[g] += e * bp[j * 5 + g];
  }
  float inv = 1.0f / d;
#pragma unroll
  for (int g = 0; g < 5; ++g) outv[OUTOFF + g] = p5[g] * inv;
}

#define DRAIN_SYNC()                                  \
  do {                                                \
    asm volatile("s_waitcnt vmcnt(0)" ::: "memory");  \
    __syncthreads();                                  \
  } while (0)

__global__ __launch_bounds__(128, 1) void meso_kernel(
    const float* __restrict__ x, const float* __restrict__ w,
    float* __restrict__ out) {
  __shared__ __align__(16) float sm[16128];  // 64512 B
  const int t = threadIdx.x;
  const int row0 = blockIdx.x * 128;

  // prologue: stage unit0 (seg L=12 @src 330), region [0,7808)
  stage_unit<61, 60, 330, 0>(x, row0, t, sm);

  // M = W W^T while the first stage is in flight
  float W[5][10];
#pragma unroll
  for (int g = 0; g < 5; ++g)
#pragma unroll
    for (int h = 0; h < 10; ++h) W[g][h] = w[g * 10 + h];
  float M[5][5];
#pragma unroll
  for (int g = 0; g < 5; ++g)
#pragma unroll
    for (int gp = 0; gp < 5; ++gp) {
      float a = 0.f;
#pragma unroll
      for (int h = 0; h < 10; ++h) a += W[g][h] * W[gp][h];
      M[g][gp] = a;
    }

  float outv[35];
  DRAIN_SYNC();

  // phase 0: stage u1 (L=5 @0 -> lds 12928) || compute u0 (L=12) -> out[30..]
  stage_unit<25, 25, 0, 12928>(x, row0, t, sm);
  compute_seg<12, 61, 0, 30>(sm, t, M, outv);
  DRAIN_SYNC();

  // phase 1: stage u2 (L=9 @25 -> 0) || compute u1 (L=5) -> out[0..]
  stage_unit<45, 45, 25, 0>(x, row0, t, sm);
  compute_seg<5, 25, 12928, 0>(sm, t, M, outv);
  DRAIN_SYNC();

  // phase 2: stage u3 (L=9 @70 -> 10368) || compute u2 -> out[5..]
  stage_unit<45, 45, 70, 10368>(x, row0, t, sm);
  compute_seg<9, 45, 0, 5>(sm, t, M, outv);
  DRAIN_SYNC();

  // phase 3: stage u4 (L=9 @240 -> 0) || compute u3 -> out[10..]
  stage_unit<45, 45, 240, 0>(x, row0, t, sm);
  compute_seg<9, 45, 10368, 10>(sm, t, M, outv);
  DRAIN_SYNC();

  // phase 4: stage u5 (L=9 @285 -> 10368) || compute u4 -> out[20..]
  stage_unit<45, 45, 285, 10368>(x, row0, t, sm);
  compute_seg<9, 45, 0, 20>(sm, t, M, outv);
  DRAIN_SYNC();

  // phase 5: stage u6 (25A: 16 j's @115 -> 0, P=81) || compute u5 -> out[25..]
  stage_unit<81, 80, 115, 0>(x, row0, t, sm);
  compute_seg<9, 45, 10368, 25>(sm, t, M, outv);
  DRAIN_SYNC();

  // phase 6: stage u7 (25B: 9 j's @195 -> 10368) || partial ss over 25A
  stage_unit<45, 45, 195, 10368>(x, row0, t, sm);
  float ssp[5] = {0.f, 0.f, 0.f, 0.f, 0.f};
  {
    const float* bpA = sm + t * 81;
#pragma unroll
    for (int j = 0; j < 16; ++j)
#pragma unroll
      for (int g = 0; g < 5; ++g) ssp[g] += bpA[j * 5 + g];
  }
  DRAIN_SYNC();

  // phase 7: finish seg3 (L=25) -> out[15..]
  {
    const float* bpA = sm + t * 81;           // j = 0..15
    const float* bpB = sm + 10368 + t * 45;   // j = 16..24
#pragma unroll
    for (int j = 0; j < 9; ++j)
#pragma unroll
      for (int g = 0; g < 5; ++g) ssp[g] += bpB[j * 5 + g];

    float v[5];
#pragma unroll
    for (int g = 0; g < 5; ++g) {
      float a = 0.f;
#pragma unroll
      for (int h = 0; h < 5; ++h) a += M[g][h] * ssp[h];
      v[g] = a;
    }

    float sc[25];
    float m = -1e30f;
#pragma unroll
    for (int j = 0; j < 25; ++j) {
      const float* bp = (j < 16) ? (bpA + j * 5) : (bpB + (j - 16) * 5);
      float a = 0.f;
#pragma unroll
      for (int g = 0; g < 5; ++g) a += bp[g] * v[g];
      sc[j] = a;
      m = fmaxf(m, a);
    }

    float d = 0.f, p5[5] = {0.f, 0.f, 0.f, 0.f, 0.f};
#pragma unroll
    for (int j = 0; j < 25; ++j) {
      const float* bp = (j < 16) ? (bpA + j * 5) : (bpB + (j - 16) * 5);
      float e = __expf(sc[j] - m);
      d += e;
#pragma unroll
      for (int g = 0; g < 5; ++g) p5[g] += e * bp[g];
    }
    float inv = 1.0f / d;
#pragma unroll
    for (int g = 0; g < 5; ++g) outv[15 + g] = p5[g] * inv;
  }
  __syncthreads();  // all LDS reads done before out-staging reuses region 0

  // out staging: coalesced write. 128 rows x 35 floats = 4480 fl = 1120 float4
#pragma unroll
  for (int c = 0; c < 35; ++c) sm[t * 35 + c] = outv[c];
  __syncthreads();

  const float4* s4 = (const float4*)sm;
  float4* o4 = (float4*)(out + (size_t)blockIdx.x * 4480);
#pragma unroll
  for (int i = 0; i < 9; ++i) {
    int idx = i * 128 + t;
    if (idx < 1120) o4[idx] = s4[idx];
  }
}

extern "C" void kernel_launch(void* const* d_in, const int* in_sizes, int n_in,
                              void* d_out, int out_size, void* d_ws, size_t ws_size,
                              hipStream_t stream) {
  const float* x = (const float*)d_in[0];
  const float* w = (const float*)d_in[1];
  float* out = (float*)d_out;
  int B = in_sizes[0] / 390;  // 131072
  int grid = B / 128;         // 1024 blocks
  meso_kernel<<<grid, 128, 0, stream>>>(x, w, out);
}

// Round 4
// 61.098 us; speedup vs baseline: 1.1603x; 1.0513x over previous
//
#include <hip/hip_runtime.h>

// MesoLayer, flat-chunk staged, counted-vmcnt pipeline (R2 bug fixed).
// Block = 256 threads, 256 rows, 16 chunks of 16 rows. The block's x panel
// (256*390 floats) is contiguous -> staged as flat float4 via
// global_load_lds width=16 with PER-LANE LDS pointers (readfirstlane gives
// each wave its correct base; uniform base was R2's corruption bug).
// Double-buffered, counted s_waitcnt vmcnt(6) + raw s_barrier (loads stay in
// flight across barriers). Compute split across all 4 waves each phase.

#define GLL16(gp, lp)                                                   \
  __builtin_amdgcn_global_load_lds(                                     \
      (const __attribute__((address_space(1))) void*)(gp),              \
      (__attribute__((address_space(3))) void*)(lp), 16, 0, 0)

// Stage one 16-row chunk (1560 float4) g -> l. Per-lane LDS ptr: lane t of
// wave w gives readfirstlane base (i*256 + w*64), HW adds lane*16B.
__device__ __forceinline__ void stage_chunk(const float4* __restrict__ g,
                                            float4* l, int t, int wv) {
#pragma unroll
  for (int i = 0; i < 6; ++i) GLL16(g + i * 256 + t, l + i * 256 + t);
  if (wv == 0) {  // wave-uniform branch, all 64 lanes participate
    int idx = (t < 24) ? 1536 + t : t;  // lanes 24..63: dummy in-bounds addr
    GLL16(g + idx, l + 1536 + t);       // they land in the [1560,1600) pad
  }
}

// One segment for one row from LDS. 16 active lanes, row stride 390 floats
// (390 % 32 = 6 -> banks (r*6+c)%32 distinct over r=0..15: conflict-free).
template<int L>
__device__ __forceinline__ void seg_compute(const float* bp,
                                            const float (&M)[5][5],
                                            float* ob) {
  float ss[5] = {0.f, 0.f, 0.f, 0.f, 0.f};
#pragma unroll
  for (int j = 0; j < L; ++j)
#pragma unroll
    for (int g = 0; g < 5; ++g) ss[g] += bp[j * 5 + g];

  float v[5];
#pragma unroll
  for (int g = 0; g < 5; ++g) {
    float a = 0.f;
#pragma unroll
    for (int h = 0; h < 5; ++h) a += M[g][h] * ss[h];
    v[g] = a;
  }

  float sc[L];
  float m = -1e30f;
#pragma unroll
  for (int j = 0; j < L; ++j) {
    float a = 0.f;
#pragma unroll
    for (int g = 0; g < 5; ++g) a += bp[j * 5 + g] * v[g];
    sc[j] = a;
    m = fmaxf(m, a);
  }

  float d = 0.f, p5[5] = {0.f, 0.f, 0.f, 0.f, 0.f};
#pragma unroll
  for (int j = 0; j < L; ++j) {
    float e = __expf(sc[j] - m);
    d += e;
#pragma unroll
    for (int g = 0; g < 5; ++g) p5[g] += e * bp[j * 5 + g];
  }
  float inv = 1.0f / d;
#pragma unroll
  for (int g = 0; g < 5; ++g) ob[g] = p5[g] * inv;
}

// LDS (float4 units): buf0 [0,1600) | buf1 [1600,3200) | out [3200,3340)
__global__ __launch_bounds__(256, 2) void meso_kernel(
    const float* __restrict__ x, const float* __restrict__ w,
    float* __restrict__ out) {
  __shared__ __align__(16) float4 sm4[3340];
  float* smf = (float*)sm4;
  const int t = threadIdx.x;
  const size_t blk = blockIdx.x;
  const int wv = t >> 6, ln = t & 63, sg = ln >> 4, r = ln & 15;

  const float4* xp4 = (const float4*)x + blk * 24960;  // 256*390/4
  float4* o4 = (float4*)out + blk * 2240;              // 256*35/4

  stage_chunk(xp4, sm4, t, wv);  // chunk 0 in flight...

  // ...while computing M = W W^T (w uniform -> scalar loads, lgkm domain)
  float W[5][10];
#pragma unroll
  for (int g = 0; g < 5; ++g)
#pragma unroll
    for (int h = 0; h < 10; ++h) W[g][h] = w[g * 10 + h];
  float M[5][5];
#pragma unroll
  for (int g = 0; g < 5; ++g)
#pragma unroll
    for (int gp = 0; gp < 5; ++gp) {
      float a = 0.f;
#pragma unroll
      for (int h = 0; h < 10; ++h) a += W[g][h] * W[gp][h];
      M[g][gp] = a;
    }

#pragma unroll 1
  for (int p = 0; p < 16; ++p) {
    if (p < 15) {
      stage_chunk(xp4 + (p + 1) * 1560, sm4 + ((p + 1) & 1) * 1600, t, wv);
      // Chunk p complete when <=6 VMEM ops remain: at this point a wave has
      // outstanding <= (6 residual + 1 flush store + 7 new loads) = 14; the
      // newest 6 can only be chunk-(p+1) loads -> chunk p fully landed.
      asm volatile("s_waitcnt vmcnt(6)" ::: "memory");
    } else {
      asm volatile("s_waitcnt vmcnt(0)" ::: "memory");
    }
    __builtin_amdgcn_s_barrier();  // chunk p visible to all waves

    // Compute: all 4 waves, seg partition balances j-counts (25|17|18|18).
    {
      const float* bp = smf + (p & 1) * 6400 + r * 390;
      float* ob = smf + 12800 + r * 35;
      if (wv == 0) {
        if (sg == 0) seg_compute<25>(bp + 115, M, ob + 15);
      } else if (wv == 1) {
        if (sg == 0)      seg_compute<12>(bp + 330, M, ob + 30);
        else if (sg == 1) seg_compute<5 >(bp + 0,   M, ob + 0);
      } else if (wv == 2) {
        if (sg == 0)      seg_compute<9 >(bp + 25,  M, ob + 5);
        else if (sg == 1) seg_compute<9 >(bp + 70,  M, ob + 10);
      } else {
        if (sg == 0)      seg_compute<9 >(bp + 240, M, ob + 20);
        else if (sg == 1) seg_compute<9 >(bp + 285, M, ob + 25);
      }
    }
    asm volatile("s_waitcnt lgkmcnt(0)" ::: "memory");  // drain ob writes
    __builtin_amdgcn_s_barrier();  // outbuf visible

    // Flush 16 rows * 35 floats = 140 float4, coalesced. The ds_read's data
    // dependency (store consumes it) drains lgkm before the store issues, so
    // this read cannot race with next phase's ob writes.
    if (t < 140) o4[p * 140 + t] = sm4[3200 + t];
  }
}

extern "C" void kernel_launch(void* const* d_in, const int* in_sizes, int n_in,
                              void* d_out, int out_size, void* d_ws, size_t ws_size,
                              hipStream_t stream) {
  const float* x = (const float*)d_in[0];
  const float* w = (const float*)d_in[1];
  float* out = (float*)d_out;
  int B = in_sizes[0] / 390;  // 131072
  int grid = B / 256;         // 512 blocks = 2/CU, all resident
  meso_kernel<<<grid, 256, 0, stream>>>(x, w, out);
}